// Round 19
// baseline (201.569 us; speedup 1.0000x reference)
//
#include <hip/hip_runtime.h>

#define N_NODES 50000
#define N_EDGES 800000
#define IN_C 128
#define HID_C 256
#define OUT_C 128
#define NBLK 196   // ceil(N_NODES / 256)
#define NPART 8    // XCD count; partition width = N_NODES/8 = 6250
#define XCONV_BLKS 6250  // N_NODES*IN_C/4 / 256
#define WCONV_BLKS 128   // 32768 / 256

typedef __attribute__((ext_vector_type(8))) short short8v;  // 8 bf16
typedef __attribute__((ext_vector_type(4))) float f32x4;

static __device__ __forceinline__ unsigned short f2bf(float f) {
  unsigned int u = __float_as_uint(f);
  unsigned int r = (u + 0x7fffu + ((u >> 16) & 1u)) >> 16;  // RNE
  return (unsigned short)r;
}
static __device__ __forceinline__ float bf2f(unsigned short h) {
  return __uint_as_float(((unsigned int)h) << 16);
}
// HL format: u32 = hi_bf16 | lo_bf16<<16, hi+lo ~= 16 mantissa bits of fp32.
static __device__ __forceinline__ unsigned int packHL(float v) {
  const unsigned short h = f2bf(v);
  const unsigned short l = f2bf(v - bf2f(h));
  return (unsigned int)h | ((unsigned int)l << 16);
}
// bf16 pair packing: u32 = bf(a) | bf(b)<<16  (natural k-order pairs)
static __device__ __forceinline__ unsigned int packBF2(float a, float b) {
  return (unsigned int)f2bf(a) | ((unsigned int)f2bf(b) << 16);
}
static __device__ __forceinline__ void unpackHL_g(const unsigned int* __restrict__ p,
                                                  short8v& hi, short8v& lo) {
  const uint4 a = *(const uint4*)p;
  const uint4 b = *(const uint4*)(p + 4);
  union { unsigned int u[4]; short8v s; } H, L;
  H.u[0] = (a.x & 0xffffu) | (a.y << 16);
  H.u[1] = (a.z & 0xffffu) | (a.w << 16);
  H.u[2] = (b.x & 0xffffu) | (b.y << 16);
  H.u[3] = (b.z & 0xffffu) | (b.w << 16);
  L.u[0] = (a.x >> 16) | (a.y & 0xffff0000u);
  L.u[1] = (a.z >> 16) | (a.w & 0xffff0000u);
  L.u[2] = (b.x >> 16) | (b.y & 0xffff0000u);
  L.u[3] = (b.z >> 16) | (b.w & 0xffff0000u);
  hi = H.s;
  lo = L.s;
}

// ---------------------------------------------------------------------------
// Edge conversion (int32/int64 auto-detect) + dst-degree histogram.
// atomicAdd return value = edge's rank within its dst-bucket; pack
// edata[e] = { dst | rank<<16 , src }. deg must be pre-zeroed (memset).
// ---------------------------------------------------------------------------
__global__ __launch_bounds__(256) void convert_count_k(const int* __restrict__ ei,
                                                       uint2* __restrict__ edata,
                                                       int* __restrict__ deg) {
  __shared__ int s_is64;
  if (threadIdx.x == 0) {
    int nz = 0;
#pragma unroll
    for (int k = 0; k < 64; ++k) nz |= ei[2 * k + 1];
    s_is64 = (nz == 0) ? 1 : 0;
  }
  __syncthreads();
  const int is64 = s_is64;
  const int e = blockIdx.x * 256 + threadIdx.x;
  if (e < N_EDGES) {
    int s, d;
    if (is64) {
      const uint2 sv = ((const uint2*)ei)[e];            // 8B load, low word = src
      const uint2 dv = ((const uint2*)ei)[N_EDGES + e];  // 8B load, low word = dst
      s = (int)sv.x;
      d = (int)dv.x;
    } else {
      s = ei[e];
      d = ei[N_EDGES + e];
    }
    const int r = atomicAdd(&deg[d], 1);  // rank within bucket
    const uint2 t = {(unsigned int)d | ((unsigned int)r << 16), (unsigned int)s};
    edata[e] = t;
  }
}

// ---------------------------------------------------------------------------
// Parallel 3-phase exclusive scan over deg (bsum / bscan / bfinal+dinv).
// ---------------------------------------------------------------------------
__global__ __launch_bounds__(256) void bsum_k(const int* __restrict__ deg,
                                              int* __restrict__ bsum) {
  const int i = blockIdx.x * 256 + threadIdx.x;
  int v = (i < N_NODES) ? deg[i] : 0;
#pragma unroll
  for (int off = 32; off > 0; off >>= 1) v += __shfl_down(v, off, 64);
  __shared__ int ws[4];
  if ((threadIdx.x & 63) == 0) ws[threadIdx.x >> 6] = v;
  __syncthreads();
  if (threadIdx.x == 0) bsum[blockIdx.x] = ws[0] + ws[1] + ws[2] + ws[3];
}

__global__ __launch_bounds__(256) void bscan_k(const int* __restrict__ bsum,
                                               int* __restrict__ boff) {
  __shared__ int s[256];
  const int t = threadIdx.x;
  const int v = (t < NBLK) ? bsum[t] : 0;
  s[t] = v;
  __syncthreads();
  for (int off = 1; off < 256; off <<= 1) {
    const int tmp = (t >= off) ? s[t - off] : 0;
    __syncthreads();
    s[t] += tmp;
    __syncthreads();
  }
  if (t < NBLK) boff[t] = s[t] - v;
}

__global__ __launch_bounds__(256) void bfinal_k(const int* __restrict__ deg,
                                                const int* __restrict__ boff,
                                                int* __restrict__ rowstart,
                                                float* __restrict__ dinv) {
  __shared__ int s[256];
  const int t = threadIdx.x;
  const int i = blockIdx.x * 256 + t;
  const int d = (i < N_NODES) ? deg[i] : 0;
  s[t] = d;
  __syncthreads();
  for (int off = 1; off < 256; off <<= 1) {
    const int tmp = (t >= off) ? s[t - off] : 0;
    __syncthreads();
    s[t] += tmp;
    __syncthreads();
  }
  const int run = boff[blockIdx.x] + s[t] - d;
  if (i < N_NODES) {
    rowstart[i] = run;
    dinv[i] = rsqrtf((float)d + 1.0f);
    if (i == N_NODES - 1) rowstart[N_NODES] = run + d;
  }
}

// ---------------------------------------------------------------------------
// XCD-partitioned, atomic-free CSR fill (partition p = bx&7 => one dst-range
// per XCD; bucket-contiguous csr lines coalesce in that XCD's L2).
// ---------------------------------------------------------------------------
__global__ __launch_bounds__(256) void fill_csr_part_k(const uint2* __restrict__ edata,
                                                       const int* __restrict__ rowstart,
                                                       int* __restrict__ csr_src) {
  const int p = blockIdx.x & 7;
  const int e = (blockIdx.x >> 3) * 256 + threadIdx.x;
  if (e < N_EDGES) {
    const uint2 t = edata[e];
    const int d = t.x & 0xffff;
    const int r = t.x >> 16;
    if (d / 6250 == p) csr_src[rowstart[d] + r] = (int)t.y;
  }
}

// ---------------------------------------------------------------------------
// Fused operand conversion: blocks [0,6250) convert x -> packed bf16;
// [6250,6378) split W1 -> HL; [6378,6506) split W2 -> HL.
// ---------------------------------------------------------------------------
__global__ __launch_bounds__(256) void conv_all_k(const float* __restrict__ x,
                                                  unsigned int* __restrict__ xbf,
                                                  const float* __restrict__ W1,
                                                  unsigned int* __restrict__ w1hl,
                                                  const float* __restrict__ W2,
                                                  unsigned int* __restrict__ w2hl) {
  const int b = blockIdx.x;
  if (b < XCONV_BLKS) {
    const int i = b * 256 + threadIdx.x;  // over N*C/4 float4s
    const float4 f = *(const float4*)(x + (long)i * 4);
    uint2 u = {packBF2(f.x, f.y), packBF2(f.z, f.w)};
    *(uint2*)(xbf + (long)i * 2) = u;
  } else if (b < XCONV_BLKS + WCONV_BLKS) {
    const int i = (b - XCONV_BLKS) * 256 + threadIdx.x;
    w1hl[i] = packHL(W1[i]);
  } else {
    const int i = (b - XCONV_BLKS - WCONV_BLKS) * 256 + threadIdx.x;
    w2hl[i] = packHL(W2[i]);
  }
}

// ---------------------------------------------------------------------------
// FUSED both-layer GEMM, NT=32 nodes/block (LDS 25.6 KB -> 6 blocks/CU):
//   GEMM1: h1 = relu(aggx @ W1^T + b1)   (K=128, M=256) -> LDS (bf16 packed)
//   GEMM2: h2 = h1 @ W2^T                (K=256, M=128) -> global bf16 packed
// aggx staged in LDS once; h1 NEVER touches HBM. W1/W2 HL from L2.
// Swapped MFMA operand order (m89-verified): lane's 4 acc = 4 consecutive m
// for one n.
// ---------------------------------------------------------------------------
__global__ __launch_bounds__(256) void gemm_fused_k(
    const unsigned int* __restrict__ X,     // aggx bf16-packed [N][64]
    const unsigned int* __restrict__ W1HL,  // [256][128] HL
    const float* __restrict__ b1,
    const unsigned int* __restrict__ W2HL,  // [128][256] HL
    unsigned int* __restrict__ outBF) {     // h2 bf16-packed [N][64]
  constexpr int NT = 32;    // nodes per block
  constexpr int KP1 = 68;   // aggx LDS row stride (64 + 4 pad)
  constexpr int HP = 132;   // h1 LDS row stride (128 + 4 pad)
  __shared__ unsigned int xs[NT * KP1];   // 8.7 KB
  __shared__ unsigned int h1s[NT * HP];   // 16.9 KB

  const int tid = threadIdx.x;
  const int w = tid >> 6;
  const int l = tid & 63;
  const long nbase = (long)blockIdx.x * NT;
  const int kg = (l >> 4) * 8;
  const int lr = l & 15;
  const int mq0 = (l >> 4) * 4;

  // ---- Stage aggx tile: 32 rows x 64 u32 ----
#pragma unroll
  for (int i = 0; i < 2; ++i) {
    const int idx = (tid + i * 256) * 4;
    const int row = idx >> 6, col = idx & 63;
    long gr = nbase + row;
    if (gr > N_NODES - 1) gr = N_NODES - 1;  // clamp; final stores guarded
    const uint4 v = *(const uint4*)(X + gr * 64 + col);
    *(uint4*)(xs + row * KP1 + col) = v;
  }
  __syncthreads();

  // ---- GEMM1: wave w owns m in [w*64, w*64+64), K=128 ----
  {
    const int m0w = w * 64;
    f32x4 acc[2][4];
#pragma unroll
    for (int nt = 0; nt < 2; ++nt)
#pragma unroll
      for (int mt = 0; mt < 4; ++mt) acc[nt][mt] = {0.0f, 0.0f, 0.0f, 0.0f};

#pragma unroll
    for (int ks = 0; ks < 4; ++ks) {
      const int ko = ks * 32 + kg;
      short8v wHi[4], wLo[4];
#pragma unroll
      for (int mt = 0; mt < 4; ++mt)
        unpackHL_g(W1HL + (long)(m0w + mt * 16 + lr) * IN_C + ko, wHi[mt], wLo[mt]);
#pragma unroll
      for (int nt = 0; nt < 2; ++nt) {
        const short8v xb = *(const short8v*)(xs + (nt * 16 + lr) * KP1 + ko / 2);
#pragma unroll
        for (int mt = 0; mt < 4; ++mt) {
          acc[nt][mt] = __builtin_amdgcn_mfma_f32_16x16x32_bf16(wHi[mt], xb,
                                                               acc[nt][mt], 0, 0, 0);
          acc[nt][mt] = __builtin_amdgcn_mfma_f32_16x16x32_bf16(wLo[mt], xb,
                                                               acc[nt][mt], 0, 0, 0);
        }
      }
    }

    // Epilogue 1: bias + relu -> packed bf16 into LDS h1s
#pragma unroll
    for (int nt = 0; nt < 2; ++nt) {
      const int nl = nt * 16 + lr;
#pragma unroll
      for (int mt = 0; mt < 4; ++mt) {
        const int mq = m0w + mt * 16 + mq0;
        const float4 bv = *(const float4*)(b1 + mq);
        const float v0 = fmaxf(acc[nt][mt][0] + bv.x, 0.0f);
        const float v1 = fmaxf(acc[nt][mt][1] + bv.y, 0.0f);
        const float v2 = fmaxf(acc[nt][mt][2] + bv.z, 0.0f);
        const float v3 = fmaxf(acc[nt][mt][3] + bv.w, 0.0f);
        uint2 o = {packBF2(v0, v1), packBF2(v2, v3)};
        *(uint2*)(h1s + nl * HP + mq / 2) = o;
      }
    }
  }
  __syncthreads();

  // ---- GEMM2: wave w owns m in [w*32, w*32+32), K=256 from LDS h1s ----
  {
    const int m0w = w * 32;
    f32x4 acc[2][2];
#pragma unroll
    for (int nt = 0; nt < 2; ++nt)
#pragma unroll
      for (int mt = 0; mt < 2; ++mt) acc[nt][mt] = {0.0f, 0.0f, 0.0f, 0.0f};

#pragma unroll
    for (int ks = 0; ks < 8; ++ks) {
      const int ko = ks * 32 + kg;
      short8v wHi[2], wLo[2];
#pragma unroll
      for (int mt = 0; mt < 2; ++mt)
        unpackHL_g(W2HL + (long)(m0w + mt * 16 + lr) * HID_C + ko, wHi[mt], wLo[mt]);
#pragma unroll
      for (int nt = 0; nt < 2; ++nt) {
        const short8v xb = *(const short8v*)(h1s + (nt * 16 + lr) * HP + ko / 2);
#pragma unroll
        for (int mt = 0; mt < 2; ++mt) {
          acc[nt][mt] = __builtin_amdgcn_mfma_f32_16x16x32_bf16(wHi[mt], xb,
                                                               acc[nt][mt], 0, 0, 0);
          acc[nt][mt] = __builtin_amdgcn_mfma_f32_16x16x32_bf16(wLo[mt], xb,
                                                               acc[nt][mt], 0, 0, 0);
        }
      }
    }

    // Epilogue 2: packed bf16 h2 to global
#pragma unroll
    for (int nt = 0; nt < 2; ++nt) {
      const long n = nbase + nt * 16 + lr;
      if (n < N_NODES) {
#pragma unroll
        for (int mt = 0; mt < 2; ++mt) {
          const int mq = m0w + mt * 16 + mq0;
          uint2 o = {packBF2(acc[nt][mt][0], acc[nt][mt][1]),
                     packBF2(acc[nt][mt][2], acc[nt][mt][3])};
          *(uint2*)(outBF + n * (OUT_C / 2) + mq / 2) = o;
        }
      }
    }
  }
}

// ---------------------------------------------------------------------------
// Gather-aggregate (one wave per destination node) over PACKED-BF16 rows.
// Lane reads 1 u32 = 2 channels per row. 8-edge unroll for MLP.
// OUT_BF: write packed bf16 u32 (feeds fused GEMM). Else fp32 (+bias) final.
// ---------------------------------------------------------------------------
template <int C, bool HAS_BIAS, bool OUT_BF>
__global__ __launch_bounds__(256) void gather_k(const int* __restrict__ rowstart,
                                                const int* __restrict__ csr_src,
                                                const float* __restrict__ dinv,
                                                const unsigned int* __restrict__ hbf,
                                                const float* __restrict__ bias,
                                                float* __restrict__ out,
                                                unsigned int* __restrict__ outBF) {
  const int v = (blockIdx.x * 256 + threadIdx.x) >> 6;
  if (v >= N_NODES) return;
  const int lane = threadIdx.x & 63;
  constexpr int CW = C / 2;  // u32 words per row
  const int rs = rowstart[v];
  const int re = rowstart[v + 1];
  const float dv = dinv[v];

  float a0 = 0.0f, a1 = 0.0f;

  int e = rs;
  for (; e + 7 < re; e += 8) {
    int s[8];
    float nn[8];
    unsigned int r[8];
#pragma unroll
    for (int j = 0; j < 8; ++j) s[j] = csr_src[e + j];
#pragma unroll
    for (int j = 0; j < 8; ++j) nn[j] = dv * dinv[s[j]];
#pragma unroll
    for (int j = 0; j < 8; ++j) r[j] = hbf[(long)s[j] * CW + lane];
#pragma unroll
    for (int j = 0; j < 8; ++j) {
      a0 += nn[j] * bf2f((unsigned short)r[j]);
      a1 += nn[j] * bf2f((unsigned short)(r[j] >> 16));
    }
  }
  for (; e + 3 < re; e += 4) {
    int s[4];
    float nn[4];
    unsigned int r[4];
#pragma unroll
    for (int j = 0; j < 4; ++j) s[j] = csr_src[e + j];
#pragma unroll
    for (int j = 0; j < 4; ++j) nn[j] = dv * dinv[s[j]];
#pragma unroll
    for (int j = 0; j < 4; ++j) r[j] = hbf[(long)s[j] * CW + lane];
#pragma unroll
    for (int j = 0; j < 4; ++j) {
      a0 += nn[j] * bf2f((unsigned short)r[j]);
      a1 += nn[j] * bf2f((unsigned short)(r[j] >> 16));
    }
  }
  for (; e < re; ++e) {
    const int s0 = csr_src[e];
    const float n0 = dv * dinv[s0];
    const unsigned int r0 = hbf[(long)s0 * CW + lane];
    a0 += n0 * bf2f((unsigned short)r0);
    a1 += n0 * bf2f((unsigned short)(r0 >> 16));
  }

  const float s2 = dv * dv;
  const unsigned int hv = hbf[(long)v * CW + lane];
  float o0 = s2 * bf2f((unsigned short)hv) + a0;
  float o1 = s2 * bf2f((unsigned short)(hv >> 16)) + a1;
  if (HAS_BIAS) {
    const float2 bv = *(const float2*)(bias + lane * 2);
    o0 += bv.x;
    o1 += bv.y;
  }
  if (OUT_BF) {
    outBF[(long)v * CW + lane] = packBF2(o0, o1);
  } else {
    const float2 o = {o0, o1};
    *(float2*)(out + (long)v * CW * 2 + lane * 2) = o;
  }
}

// ---------------------------------------------------------------------------
extern "C" void kernel_launch(void* const* d_in, const int* in_sizes, int n_in,
                              void* d_out, int out_size, void* d_ws, size_t ws_size,
                              hipStream_t stream) {
  (void)in_sizes; (void)n_in; (void)out_size; (void)ws_size;

  const float* x  = (const float*)d_in[0];
  const int*   ei = (const int*)d_in[1];
  const float* W1 = (const float*)d_in[2];
  const float* b1 = (const float*)d_in[3];
  const float* W2 = (const float*)d_in[4];
  const float* b2 = (const float*)d_in[5];
  float* out = (float*)d_out;

  // Workspace layout (bytes):
  char* ws = (char*)d_ws;
  uint2* edata    = (uint2*)(ws + 0);          //  6.4 MB {dst|rank<<16, src}
  int*   csr_src  = (int*)(ws + 6400000);      //  3.2 MB
  int*   deg      = (int*)(ws + 9600000);      //  0.2 MB
  int*   rowstart = (int*)(ws + 9800000);      //  0.2 MB (N+1)
  float* dinv     = (float*)(ws + 10000016);   //  0.2 MB
  int*   bsum     = (int*)(ws + 10200016);
  int*   boff     = (int*)(ws + 10201040);
  unsigned int* w1hl   = (unsigned int*)(ws + 10300000);  // 131 KB
  unsigned int* w2hl   = (unsigned int*)(ws + 10500000);  // 131 KB
  unsigned int* aggxbf = (unsigned int*)(ws + 11000000);  // 12.8 MB (bf16 packed)
  unsigned int* h2bf   = (unsigned int*)(ws + 24000000);  // 12.8 MB (bf16 packed)
  unsigned int* xbf    = (unsigned int*)(ws + 91200000);  // 12.8 MB

  const int EB = (N_EDGES + 255) / 256;  // 3125
  const int GB = (N_NODES + 3) / 4;      // gather: 1 node/wave

  // ---- Graph preprocessing: CSR by destination + dinv ----
  hipMemsetAsync(deg, 0, N_NODES * sizeof(int), stream);
  convert_count_k<<<EB, 256, 0, stream>>>(ei, edata, deg);
  bsum_k<<<NBLK, 256, 0, stream>>>(deg, bsum);
  bscan_k<<<1, 256, 0, stream>>>(bsum, boff);
  bfinal_k<<<NBLK, 256, 0, stream>>>(deg, boff, rowstart, dinv);
  fill_csr_part_k<<<EB * NPART, 256, 0, stream>>>(edata, rowstart, csr_src);

  // ---- Fused operand conversions (x -> bf16, W1/W2 -> HL) ----
  conv_all_k<<<XCONV_BLKS + 2 * WCONV_BLKS, 256, 0, stream>>>(x, xbf, W1, w1hl,
                                                              W2, w2hl);

  // ---- Layer 1 gather: aggx = agg(x_bf16) (bf16 out) ----
  gather_k<IN_C, false, true><<<GB, 256, 0, stream>>>(
      rowstart, csr_src, dinv, xbf, nullptr, nullptr, aggxbf);

  // ---- Fused GEMM1+GEMM2: h2 = relu(aggx@W1^T + b1) @ W2^T (h1 stays in LDS)
  gemm_fused_k<<<(N_NODES + 31) / 32, 256, 0, stream>>>(aggxbf, w1hl, b1, w2hl,
                                                        h2bf);

  // ---- Layer 2 gather: out = agg(h2_bf16) + b2 ----
  gather_k<OUT_C, true, false><<<GB, 256, 0, stream>>>(
      rowstart, csr_src, dinv, h2bf, b2, out, nullptr);
}

// Round 20
// 167.768 us; speedup vs baseline: 1.2015x; 1.2015x over previous
//
#include <hip/hip_runtime.h>

#define N_NODES 50000
#define N_EDGES 800000
#define IN_C 128
#define HID_C 256
#define OUT_C 128
#define NBLK 196   // ceil(N_NODES / 256)
#define NPART 8    // XCD count; partition width = N_NODES/8 = 6250
#define XCONV_BLKS 6250  // N_NODES*IN_C/4 / 256
#define WCONV_BLKS 64    // 32768 elems -> 16384 u32 -> 64 blocks

typedef __attribute__((ext_vector_type(8))) short short8v;  // 8 bf16
typedef __attribute__((ext_vector_type(4))) float f32x4;

static __device__ __forceinline__ unsigned short f2bf(float f) {
  unsigned int u = __float_as_uint(f);
  unsigned int r = (u + 0x7fffu + ((u >> 16) & 1u)) >> 16;  // RNE
  return (unsigned short)r;
}
static __device__ __forceinline__ float bf2f(unsigned short h) {
  return __uint_as_float(((unsigned int)h) << 16);
}
// bf16 pair packing: u32 = bf(a) | bf(b)<<16  (natural k-order pairs)
static __device__ __forceinline__ unsigned int packBF2(float a, float b) {
  return (unsigned int)f2bf(a) | ((unsigned int)f2bf(b) << 16);
}

// ---------------------------------------------------------------------------
// Edge conversion (int32/int64 auto-detect) + dst-degree histogram.
// atomicAdd return value = edge's rank within its dst-bucket; pack
// edata[e] = { dst | rank<<16 , src }. deg must be pre-zeroed (memset).
// ---------------------------------------------------------------------------
__global__ __launch_bounds__(256) void convert_count_k(const int* __restrict__ ei,
                                                       uint2* __restrict__ edata,
                                                       int* __restrict__ deg) {
  __shared__ int s_is64;
  if (threadIdx.x == 0) {
    int nz = 0;
#pragma unroll
    for (int k = 0; k < 64; ++k) nz |= ei[2 * k + 1];
    s_is64 = (nz == 0) ? 1 : 0;
  }
  __syncthreads();
  const int is64 = s_is64;
  const int e = blockIdx.x * 256 + threadIdx.x;
  if (e < N_EDGES) {
    int s, d;
    if (is64) {
      const uint2 sv = ((const uint2*)ei)[e];            // 8B load, low word = src
      const uint2 dv = ((const uint2*)ei)[N_EDGES + e];  // 8B load, low word = dst
      s = (int)sv.x;
      d = (int)dv.x;
    } else {
      s = ei[e];
      d = ei[N_EDGES + e];
    }
    const int r = atomicAdd(&deg[d], 1);  // rank within bucket
    const uint2 t = {(unsigned int)d | ((unsigned int)r << 16), (unsigned int)s};
    edata[e] = t;
  }
}

// ---------------------------------------------------------------------------
// Parallel 3-phase exclusive scan over deg (bsum / bscan / bfinal+dinv).
// ---------------------------------------------------------------------------
__global__ __launch_bounds__(256) void bsum_k(const int* __restrict__ deg,
                                              int* __restrict__ bsum) {
  const int i = blockIdx.x * 256 + threadIdx.x;
  int v = (i < N_NODES) ? deg[i] : 0;
#pragma unroll
  for (int off = 32; off > 0; off >>= 1) v += __shfl_down(v, off, 64);
  __shared__ int ws[4];
  if ((threadIdx.x & 63) == 0) ws[threadIdx.x >> 6] = v;
  __syncthreads();
  if (threadIdx.x == 0) bsum[blockIdx.x] = ws[0] + ws[1] + ws[2] + ws[3];
}

__global__ __launch_bounds__(256) void bscan_k(const int* __restrict__ bsum,
                                               int* __restrict__ boff) {
  __shared__ int s[256];
  const int t = threadIdx.x;
  const int v = (t < NBLK) ? bsum[t] : 0;
  s[t] = v;
  __syncthreads();
  for (int off = 1; off < 256; off <<= 1) {
    const int tmp = (t >= off) ? s[t - off] : 0;
    __syncthreads();
    s[t] += tmp;
    __syncthreads();
  }
  if (t < NBLK) boff[t] = s[t] - v;
}

__global__ __launch_bounds__(256) void bfinal_k(const int* __restrict__ deg,
                                                const int* __restrict__ boff,
                                                int* __restrict__ rowstart,
                                                float* __restrict__ dinv) {
  __shared__ int s[256];
  const int t = threadIdx.x;
  const int i = blockIdx.x * 256 + t;
  const int d = (i < N_NODES) ? deg[i] : 0;
  s[t] = d;
  __syncthreads();
  for (int off = 1; off < 256; off <<= 1) {
    const int tmp = (t >= off) ? s[t - off] : 0;
    __syncthreads();
    s[t] += tmp;
    __syncthreads();
  }
  const int run = boff[blockIdx.x] + s[t] - d;
  if (i < N_NODES) {
    rowstart[i] = run;
    dinv[i] = rsqrtf((float)d + 1.0f);
    if (i == N_NODES - 1) rowstart[N_NODES] = run + d;
  }
}

// ---------------------------------------------------------------------------
// XCD-partitioned, atomic-free CSR fill (partition p = bx&7 => one dst-range
// per XCD; bucket-contiguous csr lines coalesce in that XCD's L2).
// ---------------------------------------------------------------------------
__global__ __launch_bounds__(256) void fill_csr_part_k(const uint2* __restrict__ edata,
                                                       const int* __restrict__ rowstart,
                                                       int* __restrict__ csr_src) {
  const int p = blockIdx.x & 7;
  const int e = (blockIdx.x >> 3) * 256 + threadIdx.x;
  if (e < N_EDGES) {
    const uint2 t = edata[e];
    const int d = t.x & 0xffff;
    const int r = t.x >> 16;
    if (d / 6250 == p) csr_src[rowstart[d] + r] = (int)t.y;
  }
}

// ---------------------------------------------------------------------------
// Fused operand conversion: blocks [0,6250) convert x -> packed bf16;
// [6250,6314) pack W1 -> bf16 pairs; [6314,6378) pack W2 -> bf16 pairs.
// ---------------------------------------------------------------------------
__global__ __launch_bounds__(256) void conv_all_k(const float* __restrict__ x,
                                                  unsigned int* __restrict__ xbf,
                                                  const float* __restrict__ W1,
                                                  unsigned int* __restrict__ w1bf,
                                                  const float* __restrict__ W2,
                                                  unsigned int* __restrict__ w2bf) {
  const int b = blockIdx.x;
  if (b < XCONV_BLKS) {
    const int i = b * 256 + threadIdx.x;  // over N*C/4 float4s
    const float4 f = *(const float4*)(x + (long)i * 4);
    uint2 u = {packBF2(f.x, f.y), packBF2(f.z, f.w)};
    *(uint2*)(xbf + (long)i * 2) = u;
  } else if (b < XCONV_BLKS + WCONV_BLKS) {
    const int i = (b - XCONV_BLKS) * 256 + threadIdx.x;  // u32 index
    const float2 f = *(const float2*)(W1 + (long)i * 2);
    w1bf[i] = packBF2(f.x, f.y);
  } else {
    const int i = (b - XCONV_BLKS - WCONV_BLKS) * 256 + threadIdx.x;
    const float2 f = *(const float2*)(W2 + (long)i * 2);
    w2bf[i] = packBF2(f.x, f.y);
  }
}

// ---------------------------------------------------------------------------
// FUSED both-layer GEMM, NT=64 (round-18 geometry), W in plain bf16:
//   GEMM1: h1 = relu(aggx @ W1^T + b1)   (K=128, M=256) -> LDS (bf16 packed)
//   GEMM2: h2 = h1 @ W2^T                (K=256, M=128) -> global bf16 packed
// aggx staged in LDS once; h1 never touches HBM. ONE MFMA per (nt,mt) per ks
// (both operands bf16). W frags are direct short8v 16B loads (no unpack).
// Swapped MFMA operand order (m89-verified): lane's 4 acc = 4 consecutive m
// for one n.
// ---------------------------------------------------------------------------
__global__ __launch_bounds__(256) void gemm_fused_k(
    const unsigned int* __restrict__ X,     // aggx bf16-packed [N][64]
    const unsigned int* __restrict__ W1BF,  // [256][64] bf16-pairs
    const float* __restrict__ b1,
    const unsigned int* __restrict__ W2BF,  // [128][128] bf16-pairs
    unsigned int* __restrict__ outBF) {     // h2 bf16-packed [N][64]
  constexpr int KP1 = 68;   // aggx LDS row stride (64 + 4 pad)
  constexpr int HP = 132;   // h1 LDS row stride (128 + 4 pad)
  __shared__ unsigned int xs[64 * KP1];   // 17.4 KB
  __shared__ unsigned int h1s[64 * HP];   // 33.8 KB

  const int tid = threadIdx.x;
  const int w = tid >> 6;
  const int l = tid & 63;
  const long nbase = (long)blockIdx.x * 64;
  const int kg = (l >> 4) * 8;
  const int lr = l & 15;
  const int mq0 = (l >> 4) * 4;

  // ---- Stage aggx tile: 64 rows x 64 u32 ----
#pragma unroll
  for (int i = 0; i < 4; ++i) {
    const int idx = (tid + i * 256) * 4;
    const int row = idx >> 6, col = idx & 63;
    long gr = nbase + row;
    if (gr > N_NODES - 1) gr = N_NODES - 1;  // clamp; final stores guarded
    const uint4 v = *(const uint4*)(X + gr * 64 + col);
    *(uint4*)(xs + row * KP1 + col) = v;
  }
  __syncthreads();

  // ---- GEMM1: wave w owns m in [w*64, w*64+64), K=128 ----
  {
    const int m0w = w * 64;
    f32x4 acc[4][4];
#pragma unroll
    for (int nt = 0; nt < 4; ++nt)
#pragma unroll
      for (int mt = 0; mt < 4; ++mt) acc[nt][mt] = {0.0f, 0.0f, 0.0f, 0.0f};

#pragma unroll
    for (int ks = 0; ks < 4; ++ks) {
      const int ko = ks * 32 + kg;  // bf16-element offset; /2 = u32 offset
      short8v wb[4];
#pragma unroll
      for (int mt = 0; mt < 4; ++mt)
        wb[mt] = *(const short8v*)(W1BF + (long)(m0w + mt * 16 + lr) * (IN_C / 2) +
                                   ko / 2);
#pragma unroll
      for (int nt = 0; nt < 4; ++nt) {
        const short8v xb = *(const short8v*)(xs + (nt * 16 + lr) * KP1 + ko / 2);
#pragma unroll
        for (int mt = 0; mt < 4; ++mt)
          acc[nt][mt] = __builtin_amdgcn_mfma_f32_16x16x32_bf16(wb[mt], xb,
                                                               acc[nt][mt], 0, 0, 0);
      }
    }

    // Epilogue 1: bias + relu -> packed bf16 into LDS h1s
#pragma unroll
    for (int nt = 0; nt < 4; ++nt) {
      const int nl = nt * 16 + lr;
#pragma unroll
      for (int mt = 0; mt < 4; ++mt) {
        const int mq = m0w + mt * 16 + mq0;
        const float4 bv = *(const float4*)(b1 + mq);
        const float v0 = fmaxf(acc[nt][mt][0] + bv.x, 0.0f);
        const float v1 = fmaxf(acc[nt][mt][1] + bv.y, 0.0f);
        const float v2 = fmaxf(acc[nt][mt][2] + bv.z, 0.0f);
        const float v3 = fmaxf(acc[nt][mt][3] + bv.w, 0.0f);
        uint2 o = {packBF2(v0, v1), packBF2(v2, v3)};
        *(uint2*)(h1s + nl * HP + mq / 2) = o;
      }
    }
  }
  __syncthreads();

  // ---- GEMM2: wave w owns m in [w*32, w*32+32), K=256 from LDS h1s ----
  {
    const int m0w = w * 32;
    f32x4 acc[4][2];
#pragma unroll
    for (int nt = 0; nt < 4; ++nt)
#pragma unroll
      for (int mt = 0; mt < 2; ++mt) acc[nt][mt] = {0.0f, 0.0f, 0.0f, 0.0f};

#pragma unroll
    for (int ks = 0; ks < 8; ++ks) {
      const int ko = ks * 32 + kg;
      short8v wb[2];
#pragma unroll
      for (int mt = 0; mt < 2; ++mt)
        wb[mt] = *(const short8v*)(W2BF + (long)(m0w + mt * 16 + lr) * (HID_C / 2) +
                                   ko / 2);
#pragma unroll
      for (int nt = 0; nt < 4; ++nt) {
        const short8v xb = *(const short8v*)(h1s + (nt * 16 + lr) * HP + ko / 2);
#pragma unroll
        for (int mt = 0; mt < 2; ++mt)
          acc[nt][mt] = __builtin_amdgcn_mfma_f32_16x16x32_bf16(wb[mt], xb,
                                                               acc[nt][mt], 0, 0, 0);
      }
    }

    // Epilogue 2: packed bf16 h2 to global
#pragma unroll
    for (int nt = 0; nt < 4; ++nt) {
      const long n = nbase + nt * 16 + lr;
      if (n < N_NODES) {
#pragma unroll
        for (int mt = 0; mt < 2; ++mt) {
          const int mq = m0w + mt * 16 + mq0;
          uint2 o = {packBF2(acc[nt][mt][0], acc[nt][mt][1]),
                     packBF2(acc[nt][mt][2], acc[nt][mt][3])};
          *(uint2*)(outBF + n * (OUT_C / 2) + mq / 2) = o;
        }
      }
    }
  }
}

// ---------------------------------------------------------------------------
// Gather-aggregate (one wave per destination node) over PACKED-BF16 rows.
// Lane reads 1 u32 = 2 channels per row. 8-edge unroll for MLP.
// OUT_BF: write packed bf16 u32 (feeds fused GEMM). Else fp32 (+bias) final.
// ---------------------------------------------------------------------------
template <int C, bool HAS_BIAS, bool OUT_BF>
__global__ __launch_bounds__(256) void gather_k(const int* __restrict__ rowstart,
                                                const int* __restrict__ csr_src,
                                                const float* __restrict__ dinv,
                                                const unsigned int* __restrict__ hbf,
                                                const float* __restrict__ bias,
                                                float* __restrict__ out,
                                                unsigned int* __restrict__ outBF) {
  const int v = (blockIdx.x * 256 + threadIdx.x) >> 6;
  if (v >= N_NODES) return;
  const int lane = threadIdx.x & 63;
  constexpr int CW = C / 2;  // u32 words per row
  const int rs = rowstart[v];
  const int re = rowstart[v + 1];
  const float dv = dinv[v];

  float a0 = 0.0f, a1 = 0.0f;

  int e = rs;
  for (; e + 7 < re; e += 8) {
    int s[8];
    float nn[8];
    unsigned int r[8];
#pragma unroll
    for (int j = 0; j < 8; ++j) s[j] = csr_src[e + j];
#pragma unroll
    for (int j = 0; j < 8; ++j) nn[j] = dv * dinv[s[j]];
#pragma unroll
    for (int j = 0; j < 8; ++j) r[j] = hbf[(long)s[j] * CW + lane];
#pragma unroll
    for (int j = 0; j < 8; ++j) {
      a0 += nn[j] * bf2f((unsigned short)r[j]);
      a1 += nn[j] * bf2f((unsigned short)(r[j] >> 16));
    }
  }
  for (; e + 3 < re; e += 4) {
    int s[4];
    float nn[4];
    unsigned int r[4];
#pragma unroll
    for (int j = 0; j < 4; ++j) s[j] = csr_src[e + j];
#pragma unroll
    for (int j = 0; j < 4; ++j) nn[j] = dv * dinv[s[j]];
#pragma unroll
    for (int j = 0; j < 4; ++j) r[j] = hbf[(long)s[j] * CW + lane];
#pragma unroll
    for (int j = 0; j < 4; ++j) {
      a0 += nn[j] * bf2f((unsigned short)r[j]);
      a1 += nn[j] * bf2f((unsigned short)(r[j] >> 16));
    }
  }
  for (; e < re; ++e) {
    const int s0 = csr_src[e];
    const float n0 = dv * dinv[s0];
    const unsigned int r0 = hbf[(long)s0 * CW + lane];
    a0 += n0 * bf2f((unsigned short)r0);
    a1 += n0 * bf2f((unsigned short)(r0 >> 16));
  }

  const float s2 = dv * dv;
  const unsigned int hv = hbf[(long)v * CW + lane];
  float o0 = s2 * bf2f((unsigned short)hv) + a0;
  float o1 = s2 * bf2f((unsigned short)(hv >> 16)) + a1;
  if (HAS_BIAS) {
    const float2 bv = *(const float2*)(bias + lane * 2);
    o0 += bv.x;
    o1 += bv.y;
  }
  if (OUT_BF) {
    outBF[(long)v * CW + lane] = packBF2(o0, o1);
  } else {
    const float2 o = {o0, o1};
    *(float2*)(out + (long)v * CW * 2 + lane * 2) = o;
  }
}

// ---------------------------------------------------------------------------
extern "C" void kernel_launch(void* const* d_in, const int* in_sizes, int n_in,
                              void* d_out, int out_size, void* d_ws, size_t ws_size,
                              hipStream_t stream) {
  (void)in_sizes; (void)n_in; (void)out_size; (void)ws_size;

  const float* x  = (const float*)d_in[0];
  const int*   ei = (const int*)d_in[1];
  const float* W1 = (const float*)d_in[2];
  const float* b1 = (const float*)d_in[3];
  const float* W2 = (const float*)d_in[4];
  const float* b2 = (const float*)d_in[5];
  float* out = (float*)d_out;

  // Workspace layout (bytes):
  char* ws = (char*)d_ws;
  uint2* edata    = (uint2*)(ws + 0);          //  6.4 MB {dst|rank<<16, src}
  int*   csr_src  = (int*)(ws + 6400000);      //  3.2 MB
  int*   deg      = (int*)(ws + 9600000);      //  0.2 MB
  int*   rowstart = (int*)(ws + 9800000);      //  0.2 MB (N+1)
  float* dinv     = (float*)(ws + 10000016);   //  0.2 MB
  int*   bsum     = (int*)(ws + 10200016);
  int*   boff     = (int*)(ws + 10201040);
  unsigned int* w1bf   = (unsigned int*)(ws + 10300000);  // 65.5 KB
  unsigned int* w2bf   = (unsigned int*)(ws + 10400000);  // 65.5 KB
  unsigned int* aggxbf = (unsigned int*)(ws + 11000000);  // 12.8 MB (bf16 packed)
  unsigned int* h2bf   = (unsigned int*)(ws + 24000000);  // 12.8 MB (bf16 packed)
  unsigned int* xbf    = (unsigned int*)(ws + 91200000);  // 12.8 MB

  const int EB = (N_EDGES + 255) / 256;  // 3125
  const int GB = (N_NODES + 3) / 4;      // gather: 1 node/wave

  // ---- Graph preprocessing: CSR by destination + dinv ----
  hipMemsetAsync(deg, 0, N_NODES * sizeof(int), stream);
  convert_count_k<<<EB, 256, 0, stream>>>(ei, edata, deg);
  bsum_k<<<NBLK, 256, 0, stream>>>(deg, bsum);
  bscan_k<<<1, 256, 0, stream>>>(bsum, boff);
  bfinal_k<<<NBLK, 256, 0, stream>>>(deg, boff, rowstart, dinv);
  fill_csr_part_k<<<EB * NPART, 256, 0, stream>>>(edata, rowstart, csr_src);

  // ---- Fused operand conversions (x -> bf16, W1/W2 -> bf16 pairs) ----
  conv_all_k<<<XCONV_BLKS + 2 * WCONV_BLKS, 256, 0, stream>>>(x, xbf, W1, w1bf,
                                                              W2, w2bf);

  // ---- Layer 1 gather: aggx = agg(x_bf16) (bf16 out) ----
  gather_k<IN_C, false, true><<<GB, 256, 0, stream>>>(
      rowstart, csr_src, dinv, xbf, nullptr, nullptr, aggxbf);

  // ---- Fused GEMM1+GEMM2: h2 = relu(aggx@W1^T + b1) @ W2^T (h1 stays in LDS)
  gemm_fused_k<<<(N_NODES + 63) / 64, 256, 0, stream>>>(aggxbf, w1bf, b1, w2bf,
                                                        h2bf);

  // ---- Layer 2 gather: out = agg(h2_bf16) + b2 ----
  gather_k<OUT_C, true, false><<<GB, 256, 0, stream>>>(
      rowstart, csr_src, dinv, h2bf, b2, out, nullptr);
}

// Round 21
// 164.802 us; speedup vs baseline: 1.2231x; 1.0180x over previous
//
#include <hip/hip_runtime.h>

#define N_NODES 50000
#define N_EDGES 800000
#define IN_C 128
#define HID_C 256
#define OUT_C 128
#define NBLK 196   // ceil(N_NODES / 256)
#define NPART 8    // XCD count; partition width = N_NODES/8 = 6250
#define EB 3125          // edge blocks
#define XCONV_BLKS 6250  // N_NODES*IN_C/4 / 256
#define WCONV_BLKS 64    // 16384 u32 / 256

typedef __attribute__((ext_vector_type(8))) short short8v;  // 8 bf16
typedef __attribute__((ext_vector_type(4))) float f32x4;

static __device__ __forceinline__ unsigned short f2bf(float f) {
  unsigned int u = __float_as_uint(f);
  unsigned int r = (u + 0x7fffu + ((u >> 16) & 1u)) >> 16;  // RNE
  return (unsigned short)r;
}
static __device__ __forceinline__ float bf2f(unsigned short h) {
  return __uint_as_float(((unsigned int)h) << 16);
}
// bf16 pair packing: u32 = bf(a) | bf(b)<<16  (natural k-order pairs)
static __device__ __forceinline__ unsigned int packBF2(float a, float b) {
  return (unsigned int)f2bf(a) | ((unsigned int)f2bf(b) << 16);
}

// ---------------------------------------------------------------------------
__global__ __launch_bounds__(256) void deg_zero_k(int* __restrict__ deg) {
  const int i = blockIdx.x * 256 + threadIdx.x;
  if (i < N_NODES) deg[i] = 0;
}

// ---------------------------------------------------------------------------
// MERGED kernel: blocks [0,EB) = edge conversion + dst histogram (ret-atomic
// rank); blocks [EB, EB+XCONV) = x -> bf16; then W1, W2 -> bf16 pairs.
// Streaming blocks co-schedule with atomic-stalled edge blocks to fill the
// CU issue slots (convert is latency-bound: VALUBusy 0.8%, occ 59%).
// ---------------------------------------------------------------------------
__global__ __launch_bounds__(256) void convert_conv_k(
    const int* __restrict__ ei, uint2* __restrict__ edata, int* __restrict__ deg,
    const float* __restrict__ x, unsigned int* __restrict__ xbf,
    const float* __restrict__ W1, unsigned int* __restrict__ w1bf,
    const float* __restrict__ W2, unsigned int* __restrict__ w2bf) {
  const int b = blockIdx.x;
  if (b < EB) {
    // ---- edge conversion + histogram ----
    __shared__ int s_is64;
    if (threadIdx.x == 0) {
      int nz = 0;
#pragma unroll
      for (int k = 0; k < 64; ++k) nz |= ei[2 * k + 1];
      s_is64 = (nz == 0) ? 1 : 0;
    }
    __syncthreads();
    const int is64 = s_is64;
    const int e = b * 256 + threadIdx.x;
    if (e < N_EDGES) {
      int s, d;
      if (is64) {
        const uint2 sv = ((const uint2*)ei)[e];            // low word = src
        const uint2 dv = ((const uint2*)ei)[N_EDGES + e];  // low word = dst
        s = (int)sv.x;
        d = (int)dv.x;
      } else {
        s = ei[e];
        d = ei[N_EDGES + e];
      }
      const int r = atomicAdd(&deg[d], 1);  // rank within bucket
      const uint2 t = {(unsigned int)d | ((unsigned int)r << 16), (unsigned int)s};
      edata[e] = t;
    }
  } else if (b < EB + XCONV_BLKS) {
    const int i = (b - EB) * 256 + threadIdx.x;  // over N*C/4 float4s
    const float4 f = *(const float4*)(x + (long)i * 4);
    uint2 u = {packBF2(f.x, f.y), packBF2(f.z, f.w)};
    *(uint2*)(xbf + (long)i * 2) = u;
  } else if (b < EB + XCONV_BLKS + WCONV_BLKS) {
    const int i = (b - EB - XCONV_BLKS) * 256 + threadIdx.x;  // u32 index
    const float2 f = *(const float2*)(W1 + (long)i * 2);
    w1bf[i] = packBF2(f.x, f.y);
  } else {
    const int i = (b - EB - XCONV_BLKS - WCONV_BLKS) * 256 + threadIdx.x;
    const float2 f = *(const float2*)(W2 + (long)i * 2);
    w2bf[i] = packBF2(f.x, f.y);
  }
}

// ---------------------------------------------------------------------------
// Parallel 3-phase exclusive scan over deg (bsum / bscan / bfinal+dinv).
// ---------------------------------------------------------------------------
__global__ __launch_bounds__(256) void bsum_k(const int* __restrict__ deg,
                                              int* __restrict__ bsum) {
  const int i = blockIdx.x * 256 + threadIdx.x;
  int v = (i < N_NODES) ? deg[i] : 0;
#pragma unroll
  for (int off = 32; off > 0; off >>= 1) v += __shfl_down(v, off, 64);
  __shared__ int ws[4];
  if ((threadIdx.x & 63) == 0) ws[threadIdx.x >> 6] = v;
  __syncthreads();
  if (threadIdx.x == 0) bsum[blockIdx.x] = ws[0] + ws[1] + ws[2] + ws[3];
}

__global__ __launch_bounds__(256) void bscan_k(const int* __restrict__ bsum,
                                               int* __restrict__ boff) {
  __shared__ int s[256];
  const int t = threadIdx.x;
  const int v = (t < NBLK) ? bsum[t] : 0;
  s[t] = v;
  __syncthreads();
  for (int off = 1; off < 256; off <<= 1) {
    const int tmp = (t >= off) ? s[t - off] : 0;
    __syncthreads();
    s[t] += tmp;
    __syncthreads();
  }
  if (t < NBLK) boff[t] = s[t] - v;
}

__global__ __launch_bounds__(256) void bfinal_k(const int* __restrict__ deg,
                                                const int* __restrict__ boff,
                                                int* __restrict__ rowstart,
                                                float* __restrict__ dinv) {
  __shared__ int s[256];
  const int t = threadIdx.x;
  const int i = blockIdx.x * 256 + t;
  const int d = (i < N_NODES) ? deg[i] : 0;
  s[t] = d;
  __syncthreads();
  for (int off = 1; off < 256; off <<= 1) {
    const int tmp = (t >= off) ? s[t - off] : 0;
    __syncthreads();
    s[t] += tmp;
    __syncthreads();
  }
  const int run = boff[blockIdx.x] + s[t] - d;
  if (i < N_NODES) {
    rowstart[i] = run;
    dinv[i] = rsqrtf((float)d + 1.0f);
    if (i == N_NODES - 1) rowstart[N_NODES] = run + d;
  }
}

// ---------------------------------------------------------------------------
// XCD-partitioned, atomic-free CSR fill (partition p = bx&7 => one dst-range
// per XCD; bucket-contiguous csr lines coalesce in that XCD's L2).
// ---------------------------------------------------------------------------
__global__ __launch_bounds__(256) void fill_csr_part_k(const uint2* __restrict__ edata,
                                                       const int* __restrict__ rowstart,
                                                       int* __restrict__ csr_src) {
  const int p = blockIdx.x & 7;
  const int e = (blockIdx.x >> 3) * 256 + threadIdx.x;
  if (e < N_EDGES) {
    const uint2 t = edata[e];
    const int d = t.x & 0xffff;
    const int r = t.x >> 16;
    if (d / 6250 == p) csr_src[rowstart[d] + r] = (int)t.y;
  }
}

// ---------------------------------------------------------------------------
// FUSED both-layer GEMM, NT=64, W in plain bf16 (one MFMA per tile per ks):
//   GEMM1: h1 = relu(aggx @ W1^T + b1)   (K=128, M=256) -> LDS (bf16 packed)
//   GEMM2: h2 = h1 @ W2^T                (K=256, M=128) -> global bf16 packed
// aggx staged in LDS once; h1 never touches HBM.
// Swapped MFMA operand order (m89-verified): lane's 4 acc = 4 consecutive m
// for one n.
// ---------------------------------------------------------------------------
__global__ __launch_bounds__(256) void gemm_fused_k(
    const unsigned int* __restrict__ X,     // aggx bf16-packed [N][64]
    const unsigned int* __restrict__ W1BF,  // [256][64] bf16-pairs
    const float* __restrict__ b1,
    const unsigned int* __restrict__ W2BF,  // [128][128] bf16-pairs
    unsigned int* __restrict__ outBF) {     // h2 bf16-packed [N][64]
  constexpr int KP1 = 68;   // aggx LDS row stride (64 + 4 pad)
  constexpr int HP = 132;   // h1 LDS row stride (128 + 4 pad)
  __shared__ unsigned int xs[64 * KP1];   // 17.4 KB
  __shared__ unsigned int h1s[64 * HP];   // 33.8 KB

  const int tid = threadIdx.x;
  const int w = tid >> 6;
  const int l = tid & 63;
  const long nbase = (long)blockIdx.x * 64;
  const int kg = (l >> 4) * 8;
  const int lr = l & 15;
  const int mq0 = (l >> 4) * 4;

  // ---- Stage aggx tile: 64 rows x 64 u32 ----
#pragma unroll
  for (int i = 0; i < 4; ++i) {
    const int idx = (tid + i * 256) * 4;
    const int row = idx >> 6, col = idx & 63;
    long gr = nbase + row;
    if (gr > N_NODES - 1) gr = N_NODES - 1;  // clamp; final stores guarded
    const uint4 v = *(const uint4*)(X + gr * 64 + col);
    *(uint4*)(xs + row * KP1 + col) = v;
  }
  __syncthreads();

  // ---- GEMM1: wave w owns m in [w*64, w*64+64), K=128 ----
  {
    const int m0w = w * 64;
    f32x4 acc[4][4];
#pragma unroll
    for (int nt = 0; nt < 4; ++nt)
#pragma unroll
      for (int mt = 0; mt < 4; ++mt) acc[nt][mt] = {0.0f, 0.0f, 0.0f, 0.0f};

#pragma unroll
    for (int ks = 0; ks < 4; ++ks) {
      const int ko = ks * 32 + kg;  // bf16-element offset; /2 = u32 offset
      short8v wb[4];
#pragma unroll
      for (int mt = 0; mt < 4; ++mt)
        wb[mt] = *(const short8v*)(W1BF + (long)(m0w + mt * 16 + lr) * (IN_C / 2) +
                                   ko / 2);
#pragma unroll
      for (int nt = 0; nt < 4; ++nt) {
        const short8v xb = *(const short8v*)(xs + (nt * 16 + lr) * KP1 + ko / 2);
#pragma unroll
        for (int mt = 0; mt < 4; ++mt)
          acc[nt][mt] = __builtin_amdgcn_mfma_f32_16x16x32_bf16(wb[mt], xb,
                                                               acc[nt][mt], 0, 0, 0);
      }
    }

    // Epilogue 1: bias + relu -> packed bf16 into LDS h1s
#pragma unroll
    for (int nt = 0; nt < 4; ++nt) {
      const int nl = nt * 16 + lr;
#pragma unroll
      for (int mt = 0; mt < 4; ++mt) {
        const int mq = m0w + mt * 16 + mq0;
        const float4 bv = *(const float4*)(b1 + mq);
        const float v0 = fmaxf(acc[nt][mt][0] + bv.x, 0.0f);
        const float v1 = fmaxf(acc[nt][mt][1] + bv.y, 0.0f);
        const float v2 = fmaxf(acc[nt][mt][2] + bv.z, 0.0f);
        const float v3 = fmaxf(acc[nt][mt][3] + bv.w, 0.0f);
        uint2 o = {packBF2(v0, v1), packBF2(v2, v3)};
        *(uint2*)(h1s + nl * HP + mq / 2) = o;
      }
    }
  }
  __syncthreads();

  // ---- GEMM2: wave w owns m in [w*32, w*32+32), K=256 from LDS h1s ----
  {
    const int m0w = w * 32;
    f32x4 acc[4][2];
#pragma unroll
    for (int nt = 0; nt < 4; ++nt)
#pragma unroll
      for (int mt = 0; mt < 2; ++mt) acc[nt][mt] = {0.0f, 0.0f, 0.0f, 0.0f};

#pragma unroll
    for (int ks = 0; ks < 8; ++ks) {
      const int ko = ks * 32 + kg;
      short8v wb[2];
#pragma unroll
      for (int mt = 0; mt < 2; ++mt)
        wb[mt] = *(const short8v*)(W2BF + (long)(m0w + mt * 16 + lr) * (HID_C / 2) +
                                   ko / 2);
#pragma unroll
      for (int nt = 0; nt < 4; ++nt) {
        const short8v xb = *(const short8v*)(h1s + (nt * 16 + lr) * HP + ko / 2);
#pragma unroll
        for (int mt = 0; mt < 2; ++mt)
          acc[nt][mt] = __builtin_amdgcn_mfma_f32_16x16x32_bf16(wb[mt], xb,
                                                               acc[nt][mt], 0, 0, 0);
      }
    }

    // Epilogue 2: packed bf16 h2 to global
#pragma unroll
    for (int nt = 0; nt < 4; ++nt) {
      const long n = nbase + nt * 16 + lr;
      if (n < N_NODES) {
#pragma unroll
        for (int mt = 0; mt < 2; ++mt) {
          const int mq = m0w + mt * 16 + mq0;
          uint2 o = {packBF2(acc[nt][mt][0], acc[nt][mt][1]),
                     packBF2(acc[nt][mt][2], acc[nt][mt][3])};
          *(uint2*)(outBF + n * (OUT_C / 2) + mq / 2) = o;
        }
      }
    }
  }
}

// ---------------------------------------------------------------------------
// Gather-aggregate (one wave per destination node) over PACKED-BF16 rows.
// Lane reads 1 u32 = 2 channels per row. 8-edge unroll for MLP.
// OUT_BF: write packed bf16 u32 (feeds fused GEMM). Else fp32 (+bias) final.
// ---------------------------------------------------------------------------
template <int C, bool HAS_BIAS, bool OUT_BF>
__global__ __launch_bounds__(256) void gather_k(const int* __restrict__ rowstart,
                                                const int* __restrict__ csr_src,
                                                const float* __restrict__ dinv,
                                                const unsigned int* __restrict__ hbf,
                                                const float* __restrict__ bias,
                                                float* __restrict__ out,
                                                unsigned int* __restrict__ outBF) {
  const int v = (blockIdx.x * 256 + threadIdx.x) >> 6;
  if (v >= N_NODES) return;
  const int lane = threadIdx.x & 63;
  constexpr int CW = C / 2;  // u32 words per row
  const int rs = rowstart[v];
  const int re = rowstart[v + 1];
  const float dv = dinv[v];

  float a0 = 0.0f, a1 = 0.0f;

  int e = rs;
  for (; e + 7 < re; e += 8) {
    int s[8];
    float nn[8];
    unsigned int r[8];
#pragma unroll
    for (int j = 0; j < 8; ++j) s[j] = csr_src[e + j];
#pragma unroll
    for (int j = 0; j < 8; ++j) nn[j] = dv * dinv[s[j]];
#pragma unroll
    for (int j = 0; j < 8; ++j) r[j] = hbf[(long)s[j] * CW + lane];
#pragma unroll
    for (int j = 0; j < 8; ++j) {
      a0 += nn[j] * bf2f((unsigned short)r[j]);
      a1 += nn[j] * bf2f((unsigned short)(r[j] >> 16));
    }
  }
  for (; e + 3 < re; e += 4) {
    int s[4];
    float nn[4];
    unsigned int r[4];
#pragma unroll
    for (int j = 0; j < 4; ++j) s[j] = csr_src[e + j];
#pragma unroll
    for (int j = 0; j < 4; ++j) nn[j] = dv * dinv[s[j]];
#pragma unroll
    for (int j = 0; j < 4; ++j) r[j] = hbf[(long)s[j] * CW + lane];
#pragma unroll
    for (int j = 0; j < 4; ++j) {
      a0 += nn[j] * bf2f((unsigned short)r[j]);
      a1 += nn[j] * bf2f((unsigned short)(r[j] >> 16));
    }
  }
  for (; e < re; ++e) {
    const int s0 = csr_src[e];
    const float n0 = dv * dinv[s0];
    const unsigned int r0 = hbf[(long)s0 * CW + lane];
    a0 += n0 * bf2f((unsigned short)r0);
    a1 += n0 * bf2f((unsigned short)(r0 >> 16));
  }

  const float s2 = dv * dv;
  const unsigned int hv = hbf[(long)v * CW + lane];
  float o0 = s2 * bf2f((unsigned short)hv) + a0;
  float o1 = s2 * bf2f((unsigned short)(hv >> 16)) + a1;
  if (HAS_BIAS) {
    const float2 bv = *(const float2*)(bias + lane * 2);
    o0 += bv.x;
    o1 += bv.y;
  }
  if (OUT_BF) {
    outBF[(long)v * CW + lane] = packBF2(o0, o1);
  } else {
    const float2 o = {o0, o1};
    *(float2*)(out + (long)v * CW * 2 + lane * 2) = o;
  }
}

// ---------------------------------------------------------------------------
extern "C" void kernel_launch(void* const* d_in, const int* in_sizes, int n_in,
                              void* d_out, int out_size, void* d_ws, size_t ws_size,
                              hipStream_t stream) {
  (void)in_sizes; (void)n_in; (void)out_size; (void)ws_size;

  const float* x  = (const float*)d_in[0];
  const int*   ei = (const int*)d_in[1];
  const float* W1 = (const float*)d_in[2];
  const float* b1 = (const float*)d_in[3];
  const float* W2 = (const float*)d_in[4];
  const float* b2 = (const float*)d_in[5];
  float* out = (float*)d_out;

  // Workspace layout (bytes):
  char* ws = (char*)d_ws;
  uint2* edata    = (uint2*)(ws + 0);          //  6.4 MB {dst|rank<<16, src}
  int*   csr_src  = (int*)(ws + 6400000);      //  3.2 MB
  int*   deg      = (int*)(ws + 9600000);      //  0.2 MB
  int*   rowstart = (int*)(ws + 9800000);      //  0.2 MB (N+1)
  float* dinv     = (float*)(ws + 10000016);   //  0.2 MB
  int*   bsum     = (int*)(ws + 10200016);
  int*   boff     = (int*)(ws + 10201040);
  unsigned int* w1bf   = (unsigned int*)(ws + 10300000);  // 65.5 KB
  unsigned int* w2bf   = (unsigned int*)(ws + 10400000);  // 65.5 KB
  unsigned int* aggxbf = (unsigned int*)(ws + 11000000);  // 12.8 MB (bf16 packed)
  unsigned int* h2bf   = (unsigned int*)(ws + 24000000);  // 12.8 MB (bf16 packed)
  unsigned int* xbf    = (unsigned int*)(ws + 91200000);  // 12.8 MB

  const int GB = (N_NODES + 3) / 4;  // gather: 1 node/wave

  // ---- Preproc: deg zero, then merged edge-convert+histogram & conversions
  deg_zero_k<<<NBLK, 256, 0, stream>>>(deg);
  convert_conv_k<<<EB + XCONV_BLKS + 2 * WCONV_BLKS, 256, 0, stream>>>(
      ei, edata, deg, x, xbf, W1, w1bf, W2, w2bf);
  bsum_k<<<NBLK, 256, 0, stream>>>(deg, bsum);
  bscan_k<<<1, 256, 0, stream>>>(bsum, boff);
  bfinal_k<<<NBLK, 256, 0, stream>>>(deg, boff, rowstart, dinv);
  fill_csr_part_k<<<EB * NPART, 256, 0, stream>>>(edata, rowstart, csr_src);

  // ---- Layer 1 gather: aggx = agg(x_bf16) (bf16 out) ----
  gather_k<IN_C, false, true><<<GB, 256, 0, stream>>>(
      rowstart, csr_src, dinv, xbf, nullptr, nullptr, aggxbf);

  // ---- Fused GEMM1+GEMM2: h2 = relu(aggx@W1^T + b1) @ W2^T (h1 stays in LDS)
  gemm_fused_k<<<(N_NODES + 63) / 64, 256, 0, stream>>>(aggxbf, w1bf, b1, w2bf,
                                                        h2bf);

  // ---- Layer 2 gather: out = agg(h2_bf16) + b2 ----
  gather_k<OUT_C, true, false><<<GB, 256, 0, stream>>>(
      rowstart, csr_src, dinv, h2bf, b2, out, nullptr);
}